// Round 13
// baseline (520.865 us; speedup 1.0000x reference)
//
#include <hip/hip_runtime.h>
#include <stdint.h>
#include <float.h>

// x[4096,256] f32, keys[65536,256] f32, values[65536,10] f32, k=8 (hardcoded).
#define B_ROWS 4096
#define N_KEYS 65536
#define DDIM 256
#define NCH 10

#define NSPLIT 32
#define SPLIT_KEYS (N_KEYS / NSPLIT)   // 2048
#define NSTEP (SPLIT_KEYS / 16)        // 128 16-key steps

typedef float f32x4 __attribute__((ext_vector_type(4)));
typedef short bf16x8 __attribute__((ext_vector_type(8)));

static __device__ __forceinline__ unsigned short f2bf(float f) {
  unsigned u = __float_as_uint(f);
  return (unsigned short)((u + 0x7FFFu + ((u >> 16) & 1u)) >> 16);
}
static __device__ __forceinline__ unsigned ford(float f) {
  unsigned u = __float_as_uint(f);
  return u ^ ((unsigned)((int)u >> 31) | 0x80000000u);
}
static __device__ __forceinline__ float ford_inv(unsigned u) {
  unsigned m = 0x80000000u | ((u >> 31) - 1u);
  return __uint_as_float(u ^ m);
}
static __device__ __forceinline__ unsigned long long shfl_xor_u64(unsigned long long v, int m) {
  unsigned lo = __shfl_xor((unsigned)v, m, 64);
  unsigned hi = __shfl_xor((unsigned)(v >> 32), m, 64);
  return ((unsigned long long)hi << 32) | lo;
}
static __device__ __forceinline__ double shfl_xor_f64(double v, int m) {
  return __longlong_as_double((long long)shfl_xor_u64((unsigned long long)__double_as_longlong(v), m));
}

// ---------------------------------------------------------------------------
// transpose_keys: bf16 + fused ksq. Stream layout for register streaming:
// [split 0..31][step kc 0..127][s 0..7][lane 0..63][16B] (each per-step
// per-s load is a coalesced 1KB segment). Also inits counts[4096]
// (blocks 0..15) and taug[4096] (blocks 16..31).
// ---------------------------------------------------------------------------
__global__ __launch_bounds__(256) void transpose_keys(const float* __restrict__ keys,
                                                      unsigned char* __restrict__ kbf,
                                                      float* __restrict__ ksq,
                                                      unsigned int* __restrict__ counts,
                                                      unsigned int* __restrict__ taug) {
  __shared__ __align__(16) unsigned char T[128 * 512];
  const int t = threadIdx.x;
  const int lane = t & 63;
  if (blockIdx.x < 16) counts[blockIdx.x * 256 + t] = 0;
  else if (blockIdx.x < 32) taug[(blockIdx.x - 16) * 256 + t] = 0xFF7FFFFFu; // ford(FLT_MAX)
  const float4* src = (const float4*)(keys + (size_t)blockIdx.x * 128 * DDIM);
#pragma unroll
  for (int j = 0; j < 32; ++j) {
    int g = j * 256 + t;
    float4 v = src[g];
    int key = g >> 6;
    int u = lane >> 1, sub = lane & 1;
    unsigned lo = ((unsigned)f2bf(v.y) << 16) | f2bf(v.x);
    unsigned hi2 = ((unsigned)f2bf(v.w) << 16) | f2bf(v.z);
    unsigned long long p = ((unsigned long long)hi2 << 32) | lo;
    *(unsigned long long*)&T[key * 512 + ((u ^ (key & 7)) << 4) + (sub << 3)] = p;
    float ss = v.x * v.x + v.y * v.y + v.z * v.z + v.w * v.w;
#pragma unroll
    for (int off = 32; off; off >>= 1) ss += __shfl_xor(ss, off, 64);
    if (lane == 0) ksq[blockIdx.x * 128 + key] = ss;
  }
  __syncthreads();
  uint4* dst = (uint4*)kbf;
  const int split = blockIdx.x >> 4;        // 16 blocks (2048 keys) per split
  const int kc0 = (blockIdx.x & 15) * 8;    // 8 steps per block
#pragma unroll
  for (int j = 0; j < 16; ++j) {
    int ou = j * 256 + t;                   // 4096 units: kcl(8) x s(8) x lane(64)
    int kcl = ou >> 9, s2 = (ou >> 6) & 7, ln = ou & 63;
    int keyl = kcl * 16 + (ln & 15);
    int koct = s2 * 4 + (ln >> 4);
    dst[((size_t)split * NSTEP + kc0 + kcl) * 512 + s2 * 64 + ln] =
        *(const uint4*)&T[keyl * 512 + ((koct ^ (keyl & 7)) << 4)];
  }
}

// ---------------------------------------------------------------------------
// knn_main: NO LDS, NO barriers. 256 thr = 4 independent waves; wave owns 32
// rows (2 reg sets of 16, x pre-scaled by -2) x one 2048-key split, streaming
// A-frags L2->VGPR double-buffered 2 steps ahead. Grid 1024 = 32 rowblocks x
// 32 splits = 4 blocks/CU = 16 waves/CU (4/SIMD) free-running: r12's 22%
// occupancy (grid-capped 2/SIMD) was the latency exposure — this doubles TLP
// with the identical inner loop. bid%8=split%8 -> 4 splits (4MB) per XCD L2.
// ksq folded into MFMA C-init: scores = accumulator directly.
// Selection: tau-gated filter+append to a PER-ROW u64 pool. tau validity:
// 8 streams/(row,split) = hi(4) x parity(2); max of their running minima >=
// v8(split) >= v8(global); taug[row] = atomicMin merge across 32 splits,
// merged value taken from the atomic's RETURN (no stale plain loads).
// Overflow (cnt>CAP) -> exact full rescan in refine: correctness
// unconditional. Warmup: 16 strided steps (256-key sample) minima-only.
// ---------------------------------------------------------------------------
__global__ __launch_bounds__(256) void knn_main(
    const float* __restrict__ x,
    const unsigned char* __restrict__ kbf,
    const float* __restrict__ ksqg,
    unsigned long long* __restrict__ pool,
    unsigned int* __restrict__ counts,
    unsigned int* __restrict__ taug,
    int CAP) {
  const int t = threadIdx.x;
  const int lane = t & 63;
  const int wv = t >> 6;
  const int lo4 = lane & 15;
  const int hi = lane >> 4;

  const int split = blockIdx.x & (NSPLIT - 1);
  const int rbb = (blockIdx.x >> 5) * 128;
  const int sb = split * SPLIT_KEYS;

  const int row0 = rbb + wv * 32 + lo4;
  const int row1 = row0 + 16;

  // ---- x fragments PRE-SCALED by -2, two 16-row sets (64 VGPR)
  bf16x8 xb0[8], xb1[8];
#pragma unroll
  for (int s = 0; s < 8; ++s) {
    const float* p0 = x + (size_t)row0 * DDIM + s * 32 + hi * 8;
    const float* p1 = x + (size_t)row1 * DDIM + s * 32 + hi * 8;
    float4 a = *(const float4*)p0, b = *(const float4*)(p0 + 4);
    float4 c = *(const float4*)p1, d = *(const float4*)(p1 + 4);
    union { unsigned short us[8]; bf16x8 v; } u0, u1;
    u0.us[0]=f2bf(-2.f*a.x); u0.us[1]=f2bf(-2.f*a.y); u0.us[2]=f2bf(-2.f*a.z); u0.us[3]=f2bf(-2.f*a.w);
    u0.us[4]=f2bf(-2.f*b.x); u0.us[5]=f2bf(-2.f*b.y); u0.us[6]=f2bf(-2.f*b.z); u0.us[7]=f2bf(-2.f*b.w);
    u1.us[0]=f2bf(-2.f*c.x); u1.us[1]=f2bf(-2.f*c.y); u1.us[2]=f2bf(-2.f*c.z); u1.us[3]=f2bf(-2.f*c.w);
    u1.us[4]=f2bf(-2.f*d.x); u1.us[5]=f2bf(-2.f*d.y); u1.us[6]=f2bf(-2.f*d.z); u1.us[7]=f2bf(-2.f*d.w);
    xb0[s] = u0.v; xb1[s] = u1.v;
  }

  const unsigned char* kb = kbf + ((size_t)split << 20) + (size_t)lane * 16;

  float m10[2] = {FLT_MAX, FLT_MAX};
  float m11[2] = {FLT_MAX, FLT_MAX};
  float tg0 = FLT_MAX, tg1 = FLT_MAX;

  bf16x8 afA[8], afB[8];
  float4 kqA, kqB;
  f32x4 a0, a1;

  auto LOADF = [&](bf16x8* af, int kc) {
    const unsigned char* p = kb + ((size_t)kc << 13);
#pragma unroll
    for (int s = 0; s < 8; ++s)
      af[s] = *(const bf16x8*)(p + (s << 10));
  };
  auto LOADQ = [&](int kc) {
    return *(const float4*)(ksqg + sb + kc * 16 + hi * 4);
  };
  auto MM = [&](const bf16x8* af, float4 kq) { // acc init = ksq (fold)
    f32x4 ini;
    ini[0] = kq.x; ini[1] = kq.y; ini[2] = kq.z; ini[3] = kq.w;
    a0 = ini; a1 = ini;
#pragma unroll
    for (int s = 0; s < 8; ++s) {
      a0 = __builtin_amdgcn_mfma_f32_16x16x32_bf16(af[s], xb0[s], a0, 0, 0, 0);
      a1 = __builtin_amdgcn_mfma_f32_16x16x32_bf16(af[s], xb1[s], a1, 0, 0, 0);
    }
  };
  auto SEL = [&](int kc, int par, bool append) {
    float mb0 = fminf(fminf(a0[0], a0[1]), fminf(a0[2], a0[3]));
    float mb1 = fminf(fminf(a1[0], a1[1]), fminf(a1[2], a1[3]));
    m10[par] = fminf(m10[par], mb0);
    m11[par] = fminf(m11[par], mb1);
    if (append) {
      const int kg = sb + kc * 16 + hi * 4;
      if (mb0 <= tg0) { // rare
#pragma unroll
        for (int i = 0; i < 4; ++i) {
          if (a0[i] <= tg0) {
            unsigned slot = atomicAdd(&counts[row0], 1u);
            if ((int)slot < CAP)
              pool[(size_t)row0 * CAP + slot] =
                  ((unsigned long long)ford(a0[i]) << 32) | (unsigned)(kg + i);
          }
        }
      }
      if (mb1 <= tg1) {
#pragma unroll
        for (int i = 0; i < 4; ++i) {
          if (a1[i] <= tg1) {
            unsigned slot = atomicAdd(&counts[row1], 1u);
            if ((int)slot < CAP)
              pool[(size_t)row1 * CAP + slot] =
                  ((unsigned long long)ford(a1[i]) << 32) | (unsigned)(kg + i);
          }
        }
      }
    }
  };
  auto PUBLISH = [&]() {
    // tau_l per row = max over 8 streams (2 parities x 4 hi-groups)
    float l0 = fmaxf(m10[0], m10[1]);
    l0 = fmaxf(l0, __shfl_xor(l0, 16, 64));
    l0 = fmaxf(l0, __shfl_xor(l0, 32, 64));
    float l1 = fmaxf(m11[0], m11[1]);
    l1 = fmaxf(l1, __shfl_xor(l1, 16, 64));
    l1 = fmaxf(l1, __shfl_xor(l1, 32, 64));
    float mg0, mg1;
    if (hi == 0) { // merge via atomic RETURN value (no stale plain loads)
      unsigned o0 = atomicMin(&taug[row0], ford(l0));
      unsigned o1 = atomicMin(&taug[row1], ford(l1));
      mg0 = fminf(ford_inv(o0), l0);
      mg1 = fminf(ford_inv(o1), l1);
    }
    mg0 = __shfl(mg0, lo4, 64); // lane (lo4, hi=0) holds the merged value
    mg1 = __shfl(mg1, lo4, 64);
    tg0 = fminf(tg0, mg0);
    tg1 = fminf(tg1, mg1);
  };

  // ---- warmup: 16 steps STRIDED by 8 (256-key sample), minima only
#pragma unroll 1
  for (int j = 0; j < 16; j += 2) {
    const int k0 = j * 8, k1 = j * 8 + 8;
    LOADF(afA, k0); kqA = LOADQ(k0);
    LOADF(afB, k1); kqB = LOADQ(k1);
    MM(afA, kqA); SEL(k0, 0, false);
    MM(afB, kqB); SEL(k1, 1, false);
  }
  PUBLISH();

  // ---- main: all 128 steps with merged tau (warmup steps redone, appending)
  LOADF(afA, 0); kqA = LOADQ(0);
  LOADF(afB, 1); kqB = LOADQ(1);
#pragma unroll 1
  for (int kc = 0; kc < NSTEP; kc += 2) {
    const int n0 = (kc + 2 < NSTEP) ? kc + 2 : 0;
    const int n1 = (kc + 3 < NSTEP) ? kc + 3 : 1;
    MM(afA, kqA);
    LOADF(afA, n0);              // prefetch 2 steps ahead
    SEL(kc, 0, true);
    kqA = LOADQ(n0);
    MM(afB, kqB);
    LOADF(afB, n1);
    SEL(kc + 1, 1, true);
    kqB = LOADQ(n1);
    if ((kc & 7) == 6) PUBLISH(); // refresh/merge tau every 8 steps
  }
}

// ---------------------------------------------------------------------------
// knn_refine: per row (1 wave): scan the row's pool (exact ford scores);
// overflow -> exact fp32 full rescan (practically never). Tournament top-24,
// fp64 recompute, true top-8 (idx tiebreak), average values.
// ---------------------------------------------------------------------------
__global__ __launch_bounds__(64) void knn_refine(
    const float* __restrict__ x,
    const float* __restrict__ keys,
    const float* __restrict__ ksq,
    const float* __restrict__ values,
    const unsigned long long* __restrict__ pool,
    const unsigned int* __restrict__ counts,
    int CAP,
    float* __restrict__ out) {
  __shared__ float4 xl[64];
  const int row = blockIdx.x;
  const int lane = threadIdx.x;

  xl[lane] = ((const float4*)(x + (size_t)row * DDIM))[lane];
  __syncthreads();

  unsigned long long h[8];
#pragma unroll
  for (int i = 0; i < 8; ++i) h[i] = ~0ULL;
  auto insert = [&](unsigned long long v) {
    if (v < h[7]) {
#pragma unroll
      for (int j = 7; j >= 1; --j) {
        unsigned long long a = h[j - 1];
        unsigned long long mx = a > v ? a : v;
        h[j] = (v < h[j]) ? mx : h[j];
      }
      h[0] = h[0] < v ? h[0] : v;
    }
  };

  const unsigned cnt = counts[row];
  if ((int)cnt <= CAP) {
    const unsigned long long* pp = pool + (size_t)row * CAP;
    for (int i = lane; i < (int)cnt; i += 64) insert(pp[i]);
  } else {
    // overflow: exact fp32 full rescan (correctness net; ~never taken)
    for (int gk = lane; gk < N_KEYS; gk += 64) {
      const float4* kr = (const float4*)(keys + (size_t)gk * DDIM);
      float acc = 0.f;
#pragma unroll 8
      for (int d = 0; d < 64; ++d) {
        float4 kv = kr[d], xv = xl[d];
        acc = fmaf(kv.x, xv.x, acc); acc = fmaf(kv.y, xv.y, acc);
        acc = fmaf(kv.z, xv.z, acc); acc = fmaf(kv.w, xv.w, acc);
      }
      float sc = fmaf(-2.0f, acc, ksq[gk]);
      insert(((unsigned long long)ford(sc) << 32) | (unsigned)gk);
    }
  }

  // ---- tournament: top-24 (u64 entries unique: gk in low bits)
  int myidx = 0;
#pragma unroll 1
  for (int r = 0; r < 24; ++r) {
    unsigned long long m = h[0];
#pragma unroll
    for (int off = 32; off; off >>= 1) {
      unsigned long long o = shfl_xor_u64(m, off);
      m = o < m ? o : m;
    }
    if (lane == r) myidx = (int)(m & 0xFFFFu);
    if (h[0] == m) {
#pragma unroll
      for (int i = 0; i < 7; ++i) h[i] = h[i + 1];
      h[7] = ~0ULL;
    }
  }

  // ---- exact fp64 distance for my candidate
  double dv = 1e300;
  if (lane < 24) {
    const float4* kr = (const float4*)(keys + (size_t)myidx * DDIM);
    double s = 0.0;
#pragma unroll 8
    for (int d = 0; d < 64; ++d) {
      float4 kv = kr[d], xv = xl[d];
      double d0 = (double)xv.x - (double)kv.x;
      double d1 = (double)xv.y - (double)kv.y;
      double d2 = (double)xv.z - (double)kv.z;
      double d3 = (double)xv.w - (double)kv.w;
      s += d0 * d0 + d1 * d1 + d2 * d2 + d3 * d3;
    }
    dv = s;
  }

  int di = myidx;
  int chosen[8];
#pragma unroll
  for (int r = 0; r < 8; ++r) {
    double m = dv; int mi = di;
#pragma unroll
    for (int off = 32; off; off >>= 1) {
      double om = shfl_xor_f64(m, off);
      int omi = __shfl_xor(mi, off, 64);
      if (om < m || (om == m && omi < mi)) { m = om; mi = omi; }
    }
    chosen[r] = mi;
    if (di == mi && dv < 1e300) dv = 1e300;
  }

  if (lane < NCH) {
    double a = 0.0;
#pragma unroll
    for (int r = 0; r < 8; ++r) a += (double)values[(size_t)chosen[r] * NCH + lane];
    out[row * NCH + lane] = (float)(a * 0.125);
  }
}

// ---------------------------------------------------------------------------
extern "C" void kernel_launch(void* const* d_in, const int* in_sizes, int n_in,
                              void* d_out, int out_size, void* d_ws, size_t ws_size,
                              hipStream_t stream) {
  (void)in_sizes; (void)n_in; (void)out_size;
  const float* x      = (const float*)d_in[0];
  const float* keys   = (const float*)d_in[1];
  const float* values = (const float*)d_in[2];
  float* out = (float*)d_out;

  char* ws = (char*)d_ws;
  unsigned char* kbf = (unsigned char*)ws;                                // 32 MB keys (stream layout)
  float*        ksq  = (float*)(ws + 33554432);                           // 256 KB
  unsigned int* counts = (unsigned int*)(ws + 33554432 + 262144);         // 16 KB (4096)
  unsigned int* taug   = (unsigned int*)(ws + 33554432 + 262144 + 16384); // 16 KB (4096)
  unsigned long long* pool =
      (unsigned long long*)(ws + 33554432 + 262144 + 32768);

  // pool budget: proven-safe floor (r1 validated writes up to 50.6 MB of ws)
  size_t base = 33554432 + 262144 + 32768;
  size_t cap = (ws_size > base) ? (ws_size - base) / ((size_t)B_ROWS * 8) : 480;
  if (cap < 480) cap = 480;    // 480 -> pool ends at 49.6 MB (< proven 50.6)
  if (cap > 1500) cap = 1500;
  int CAP = (int)cap;

  transpose_keys<<<N_KEYS / 128, 256, 0, stream>>>(keys, kbf, ksq, counts, taug);
  knn_main<<<(B_ROWS / 128) * NSPLIT, 256, 0, stream>>>(
      x, kbf, ksq, pool, counts, taug, CAP);
  knn_refine<<<B_ROWS, 64, 0, stream>>>(x, keys, ksq, values, pool, counts, CAP, out);
}

// Round 14
// 509.357 us; speedup vs baseline: 1.0226x; 1.0226x over previous
//
#include <hip/hip_runtime.h>
#include <stdint.h>
#include <float.h>

// x[4096,256] f32, keys[65536,256] f32, values[65536,10] f32, k=8 (hardcoded).
#define B_ROWS 4096
#define N_KEYS 65536
#define DDIM 256
#define NCH 10

#define NSPLIT 32
#define SPLIT_KEYS (N_KEYS / NSPLIT)   // 2048
#define NSTEP (SPLIT_KEYS / 16)        // 128 16-key steps
#define ROWS_PER_BLK 256

typedef float f32x4 __attribute__((ext_vector_type(4)));
typedef short bf16x8 __attribute__((ext_vector_type(8)));

static __device__ __forceinline__ unsigned short f2bf(float f) {
  unsigned u = __float_as_uint(f);
  return (unsigned short)((u + 0x7FFFu + ((u >> 16) & 1u)) >> 16);
}
static __device__ __forceinline__ unsigned ford(float f) {
  unsigned u = __float_as_uint(f);
  return u ^ ((unsigned)((int)u >> 31) | 0x80000000u);
}
static __device__ __forceinline__ float ford_inv(unsigned u) {
  unsigned m = 0x80000000u | ((u >> 31) - 1u);
  return __uint_as_float(u ^ m);
}
static __device__ __forceinline__ unsigned long long shfl_xor_u64(unsigned long long v, int m) {
  unsigned lo = __shfl_xor((unsigned)v, m, 64);
  unsigned hi = __shfl_xor((unsigned)(v >> 32), m, 64);
  return ((unsigned long long)hi << 32) | lo;
}
static __device__ __forceinline__ double shfl_xor_f64(double v, int m) {
  return __longlong_as_double((long long)shfl_xor_u64((unsigned long long)__double_as_longlong(v), m));
}

// ---------------------------------------------------------------------------
// transpose_keys: bf16 + fused ksq. Stream layout for register streaming:
// [split 0..31][step kc 0..127][s 0..7][lane 0..63][16B] (each per-step
// per-s load is a coalesced 1KB segment). Also inits counts[4096]
// (blocks 0..15) and taug[4096] (blocks 16..31).
// ---------------------------------------------------------------------------
__global__ __launch_bounds__(256) void transpose_keys(const float* __restrict__ keys,
                                                      unsigned char* __restrict__ kbf,
                                                      float* __restrict__ ksq,
                                                      unsigned int* __restrict__ counts,
                                                      unsigned int* __restrict__ taug) {
  __shared__ __align__(16) unsigned char T[128 * 512];
  const int t = threadIdx.x;
  const int lane = t & 63;
  if (blockIdx.x < 16) counts[blockIdx.x * 256 + t] = 0;
  else if (blockIdx.x < 32) taug[(blockIdx.x - 16) * 256 + t] = 0xFF7FFFFFu; // ford(FLT_MAX)
  const float4* src = (const float4*)(keys + (size_t)blockIdx.x * 128 * DDIM);
#pragma unroll
  for (int j = 0; j < 32; ++j) {
    int g = j * 256 + t;
    float4 v = src[g];
    int key = g >> 6;
    int u = lane >> 1, sub = lane & 1;
    unsigned lo = ((unsigned)f2bf(v.y) << 16) | f2bf(v.x);
    unsigned hi2 = ((unsigned)f2bf(v.w) << 16) | f2bf(v.z);
    unsigned long long p = ((unsigned long long)hi2 << 32) | lo;
    *(unsigned long long*)&T[key * 512 + ((u ^ (key & 7)) << 4) + (sub << 3)] = p;
    float ss = v.x * v.x + v.y * v.y + v.z * v.z + v.w * v.w;
#pragma unroll
    for (int off = 32; off; off >>= 1) ss += __shfl_xor(ss, off, 64);
    if (lane == 0) ksq[blockIdx.x * 128 + key] = ss;
  }
  __syncthreads();
  uint4* dst = (uint4*)kbf;
  const int split = blockIdx.x >> 4;        // 16 blocks (2048 keys) per split
  const int kc0 = (blockIdx.x & 15) * 8;    // 8 steps per block
#pragma unroll
  for (int j = 0; j < 16; ++j) {
    int ou = j * 256 + t;                   // 4096 units: kcl(8) x s(8) x lane(64)
    int kcl = ou >> 9, s2 = (ou >> 6) & 7, ln = ou & 63;
    int keyl = kcl * 16 + (ln & 15);
    int koct = s2 * 4 + (ln >> 4);
    dst[((size_t)split * NSTEP + kc0 + kcl) * 512 + s2 * 64 + ln] =
        *(const uint4*)&T[keyl * 512 + ((koct ^ (keyl & 7)) << 4)];
  }
}

// ---------------------------------------------------------------------------
// knn_main: NO LDS, NO barriers — 512 thr = 8 FREE-RUNNING waves (block shape
// chosen because resident blocks/CU is empirically pinned at 2: 512-thr
// blocks -> 16 waves/CU (44% occ, r5/r9) vs 256-thr -> 8 waves (22%,
// r12/r13)). Wave owns 32 rows (2 reg sets of 16, x pre-scaled by -2) x one
// 2048-key split, streaming A-frags L2->VGPR double-buffered 2 steps ahead.
// Grid 512 = 16 rowblocks(256 rows) x 32 splits; split%8 = bid%8 -> 4 splits
// (4MB) per XCD L2. ksq folded into MFMA C-init: scores = accumulator.
// Selection: tau-gated filter+append to a PER-ROW u64 pool. tau validity:
// 8 streams/(row,split) = hi(4) x parity(2); max of their running minima >=
// v8(split) >= v8(global); taug[row] = atomicMin merge across 32 splits,
// merged value taken from the atomic's RETURN (no stale plain loads).
// Overflow (cnt>CAP) -> exact full rescan in refine: correctness
// unconditional. Warmup: 16 strided steps (256-key sample) minima-only.
// ---------------------------------------------------------------------------
__global__ __launch_bounds__(512) void knn_main(
    const float* __restrict__ x,
    const unsigned char* __restrict__ kbf,
    const float* __restrict__ ksqg,
    unsigned long long* __restrict__ pool,
    unsigned int* __restrict__ counts,
    unsigned int* __restrict__ taug,
    int CAP) {
  const int t = threadIdx.x;
  const int lane = t & 63;
  const int wv = t >> 6;               // 0..7
  const int lo4 = lane & 15;
  const int hi = lane >> 4;

  const int split = blockIdx.x & (NSPLIT - 1);
  const int rbb = (blockIdx.x >> 5) * ROWS_PER_BLK;
  const int sb = split * SPLIT_KEYS;

  const int row0 = rbb + wv * 32 + lo4;
  const int row1 = row0 + 16;

  // ---- x fragments PRE-SCALED by -2, two 16-row sets (64 VGPR)
  bf16x8 xb0[8], xb1[8];
#pragma unroll
  for (int s = 0; s < 8; ++s) {
    const float* p0 = x + (size_t)row0 * DDIM + s * 32 + hi * 8;
    const float* p1 = x + (size_t)row1 * DDIM + s * 32 + hi * 8;
    float4 a = *(const float4*)p0, b = *(const float4*)(p0 + 4);
    float4 c = *(const float4*)p1, d = *(const float4*)(p1 + 4);
    union { unsigned short us[8]; bf16x8 v; } u0, u1;
    u0.us[0]=f2bf(-2.f*a.x); u0.us[1]=f2bf(-2.f*a.y); u0.us[2]=f2bf(-2.f*a.z); u0.us[3]=f2bf(-2.f*a.w);
    u0.us[4]=f2bf(-2.f*b.x); u0.us[5]=f2bf(-2.f*b.y); u0.us[6]=f2bf(-2.f*b.z); u0.us[7]=f2bf(-2.f*b.w);
    u1.us[0]=f2bf(-2.f*c.x); u1.us[1]=f2bf(-2.f*c.y); u1.us[2]=f2bf(-2.f*c.z); u1.us[3]=f2bf(-2.f*c.w);
    u1.us[4]=f2bf(-2.f*d.x); u1.us[5]=f2bf(-2.f*d.y); u1.us[6]=f2bf(-2.f*d.z); u1.us[7]=f2bf(-2.f*d.w);
    xb0[s] = u0.v; xb1[s] = u1.v;
  }

  const unsigned char* kb = kbf + ((size_t)split << 20) + (size_t)lane * 16;

  float m10[2] = {FLT_MAX, FLT_MAX};
  float m11[2] = {FLT_MAX, FLT_MAX};
  float tg0 = FLT_MAX, tg1 = FLT_MAX;

  bf16x8 afA[8], afB[8];
  float4 kqA, kqB;
  f32x4 a0, a1;

  auto LOADF = [&](bf16x8* af, int kc) {
    const unsigned char* p = kb + ((size_t)kc << 13);
#pragma unroll
    for (int s = 0; s < 8; ++s)
      af[s] = *(const bf16x8*)(p + (s << 10));
  };
  auto LOADQ = [&](int kc) {
    return *(const float4*)(ksqg + sb + kc * 16 + hi * 4);
  };
  auto MM = [&](const bf16x8* af, float4 kq) { // acc init = ksq (fold)
    f32x4 ini;
    ini[0] = kq.x; ini[1] = kq.y; ini[2] = kq.z; ini[3] = kq.w;
    a0 = ini; a1 = ini;
#pragma unroll
    for (int s = 0; s < 8; ++s) {
      a0 = __builtin_amdgcn_mfma_f32_16x16x32_bf16(af[s], xb0[s], a0, 0, 0, 0);
      a1 = __builtin_amdgcn_mfma_f32_16x16x32_bf16(af[s], xb1[s], a1, 0, 0, 0);
    }
  };
  auto SEL = [&](int kc, int par, bool append) {
    float mb0 = fminf(fminf(a0[0], a0[1]), fminf(a0[2], a0[3]));
    float mb1 = fminf(fminf(a1[0], a1[1]), fminf(a1[2], a1[3]));
    m10[par] = fminf(m10[par], mb0);
    m11[par] = fminf(m11[par], mb1);
    if (append) {
      const int kg = sb + kc * 16 + hi * 4;
      if (mb0 <= tg0) { // rare
#pragma unroll
        for (int i = 0; i < 4; ++i) {
          if (a0[i] <= tg0) {
            unsigned slot = atomicAdd(&counts[row0], 1u);
            if ((int)slot < CAP)
              pool[(size_t)row0 * CAP + slot] =
                  ((unsigned long long)ford(a0[i]) << 32) | (unsigned)(kg + i);
          }
        }
      }
      if (mb1 <= tg1) {
#pragma unroll
        for (int i = 0; i < 4; ++i) {
          if (a1[i] <= tg1) {
            unsigned slot = atomicAdd(&counts[row1], 1u);
            if ((int)slot < CAP)
              pool[(size_t)row1 * CAP + slot] =
                  ((unsigned long long)ford(a1[i]) << 32) | (unsigned)(kg + i);
          }
        }
      }
    }
  };
  auto PUBLISH = [&]() {
    // tau_l per row = max over 8 streams (2 parities x 4 hi-groups)
    float l0 = fmaxf(m10[0], m10[1]);
    l0 = fmaxf(l0, __shfl_xor(l0, 16, 64));
    l0 = fmaxf(l0, __shfl_xor(l0, 32, 64));
    float l1 = fmaxf(m11[0], m11[1]);
    l1 = fmaxf(l1, __shfl_xor(l1, 16, 64));
    l1 = fmaxf(l1, __shfl_xor(l1, 32, 64));
    float mg0, mg1;
    if (hi == 0) { // merge via atomic RETURN value (no stale plain loads)
      unsigned o0 = atomicMin(&taug[row0], ford(l0));
      unsigned o1 = atomicMin(&taug[row1], ford(l1));
      mg0 = fminf(ford_inv(o0), l0);
      mg1 = fminf(ford_inv(o1), l1);
    }
    mg0 = __shfl(mg0, lo4, 64); // lane (lo4, hi=0) holds the merged value
    mg1 = __shfl(mg1, lo4, 64);
    tg0 = fminf(tg0, mg0);
    tg1 = fminf(tg1, mg1);
  };

  // ---- warmup: 16 steps STRIDED by 8 (256-key sample), minima only
#pragma unroll 1
  for (int j = 0; j < 16; j += 2) {
    const int k0 = j * 8, k1 = j * 8 + 8;
    LOADF(afA, k0); kqA = LOADQ(k0);
    LOADF(afB, k1); kqB = LOADQ(k1);
    MM(afA, kqA); SEL(k0, 0, false);
    MM(afB, kqB); SEL(k1, 1, false);
  }
  PUBLISH();

  // ---- main: all 128 steps with merged tau (warmup steps redone, appending)
  LOADF(afA, 0); kqA = LOADQ(0);
  LOADF(afB, 1); kqB = LOADQ(1);
#pragma unroll 1
  for (int kc = 0; kc < NSTEP; kc += 2) {
    const int n0 = (kc + 2 < NSTEP) ? kc + 2 : 0;
    const int n1 = (kc + 3 < NSTEP) ? kc + 3 : 1;
    MM(afA, kqA);
    LOADF(afA, n0);              // prefetch 2 steps ahead
    SEL(kc, 0, true);
    kqA = LOADQ(n0);
    MM(afB, kqB);
    LOADF(afB, n1);
    SEL(kc + 1, 1, true);
    kqB = LOADQ(n1);
    if ((kc & 7) == 6) PUBLISH(); // refresh/merge tau every 8 steps
  }
}

// ---------------------------------------------------------------------------
// knn_refine: per row (1 wave): scan the row's pool (exact ford scores);
// overflow -> exact fp32 full rescan (practically never). Tournament top-24,
// fp64 recompute, true top-8 (idx tiebreak), average values.
// ---------------------------------------------------------------------------
__global__ __launch_bounds__(64) void knn_refine(
    const float* __restrict__ x,
    const float* __restrict__ keys,
    const float* __restrict__ ksq,
    const float* __restrict__ values,
    const unsigned long long* __restrict__ pool,
    const unsigned int* __restrict__ counts,
    int CAP,
    float* __restrict__ out) {
  __shared__ float4 xl[64];
  const int row = blockIdx.x;
  const int lane = threadIdx.x;

  xl[lane] = ((const float4*)(x + (size_t)row * DDIM))[lane];
  __syncthreads();

  unsigned long long h[8];
#pragma unroll
  for (int i = 0; i < 8; ++i) h[i] = ~0ULL;
  auto insert = [&](unsigned long long v) {
    if (v < h[7]) {
#pragma unroll
      for (int j = 7; j >= 1; --j) {
        unsigned long long a = h[j - 1];
        unsigned long long mx = a > v ? a : v;
        h[j] = (v < h[j]) ? mx : h[j];
      }
      h[0] = h[0] < v ? h[0] : v;
    }
  };

  const unsigned cnt = counts[row];
  if ((int)cnt <= CAP) {
    const unsigned long long* pp = pool + (size_t)row * CAP;
    for (int i = lane; i < (int)cnt; i += 64) insert(pp[i]);
  } else {
    // overflow: exact fp32 full rescan (correctness net; ~never taken)
    for (int gk = lane; gk < N_KEYS; gk += 64) {
      const float4* kr = (const float4*)(keys + (size_t)gk * DDIM);
      float acc = 0.f;
#pragma unroll 8
      for (int d = 0; d < 64; ++d) {
        float4 kv = kr[d], xv = xl[d];
        acc = fmaf(kv.x, xv.x, acc); acc = fmaf(kv.y, xv.y, acc);
        acc = fmaf(kv.z, xv.z, acc); acc = fmaf(kv.w, xv.w, acc);
      }
      float sc = fmaf(-2.0f, acc, ksq[gk]);
      insert(((unsigned long long)ford(sc) << 32) | (unsigned)gk);
    }
  }

  // ---- tournament: top-24 (u64 entries unique: gk in low bits)
  int myidx = 0;
#pragma unroll 1
  for (int r = 0; r < 24; ++r) {
    unsigned long long m = h[0];
#pragma unroll
    for (int off = 32; off; off >>= 1) {
      unsigned long long o = shfl_xor_u64(m, off);
      m = o < m ? o : m;
    }
    if (lane == r) myidx = (int)(m & 0xFFFFu);
    if (h[0] == m) {
#pragma unroll
      for (int i = 0; i < 7; ++i) h[i] = h[i + 1];
      h[7] = ~0ULL;
    }
  }

  // ---- exact fp64 distance for my candidate
  double dv = 1e300;
  if (lane < 24) {
    const float4* kr = (const float4*)(keys + (size_t)myidx * DDIM);
    double s = 0.0;
#pragma unroll 8
    for (int d = 0; d < 64; ++d) {
      float4 kv = kr[d], xv = xl[d];
      double d0 = (double)xv.x - (double)kv.x;
      double d1 = (double)xv.y - (double)kv.y;
      double d2 = (double)xv.z - (double)kv.z;
      double d3 = (double)xv.w - (double)kv.w;
      s += d0 * d0 + d1 * d1 + d2 * d2 + d3 * d3;
    }
    dv = s;
  }

  int di = myidx;
  int chosen[8];
#pragma unroll
  for (int r = 0; r < 8; ++r) {
    double m = dv; int mi = di;
#pragma unroll
    for (int off = 32; off; off >>= 1) {
      double om = shfl_xor_f64(m, off);
      int omi = __shfl_xor(mi, off, 64);
      if (om < m || (om == m && omi < mi)) { m = om; mi = omi; }
    }
    chosen[r] = mi;
    if (di == mi && dv < 1e300) dv = 1e300;
  }

  if (lane < NCH) {
    double a = 0.0;
#pragma unroll
    for (int r = 0; r < 8; ++r) a += (double)values[(size_t)chosen[r] * NCH + lane];
    out[row * NCH + lane] = (float)(a * 0.125);
  }
}

// ---------------------------------------------------------------------------
extern "C" void kernel_launch(void* const* d_in, const int* in_sizes, int n_in,
                              void* d_out, int out_size, void* d_ws, size_t ws_size,
                              hipStream_t stream) {
  (void)in_sizes; (void)n_in; (void)out_size;
  const float* x      = (const float*)d_in[0];
  const float* keys   = (const float*)d_in[1];
  const float* values = (const float*)d_in[2];
  float* out = (float*)d_out;

  char* ws = (char*)d_ws;
  unsigned char* kbf = (unsigned char*)ws;                                // 32 MB keys (stream layout)
  float*        ksq  = (float*)(ws + 33554432);                           // 256 KB
  unsigned int* counts = (unsigned int*)(ws + 33554432 + 262144);         // 16 KB (4096)
  unsigned int* taug   = (unsigned int*)(ws + 33554432 + 262144 + 16384); // 16 KB (4096)
  unsigned long long* pool =
      (unsigned long long*)(ws + 33554432 + 262144 + 32768);

  // pool budget: proven-safe floor (r1 validated writes up to 50.6 MB of ws)
  size_t base = 33554432 + 262144 + 32768;
  size_t cap = (ws_size > base) ? (ws_size - base) / ((size_t)B_ROWS * 8) : 480;
  if (cap < 480) cap = 480;    // 480 -> pool ends at 49.6 MB (< proven 50.6)
  if (cap > 1500) cap = 1500;
  int CAP = (int)cap;

  transpose_keys<<<N_KEYS / 128, 256, 0, stream>>>(keys, kbf, ksq, counts, taug);
  knn_main<<<(B_ROWS / ROWS_PER_BLK) * NSPLIT, 512, 0, stream>>>(
      x, kbf, ksq, pool, counts, taug, CAP);
  knn_refine<<<B_ROWS, 64, 0, stream>>>(x, keys, ksq, values, pool, counts, CAP, out);
}

// Round 15
// 306.223 us; speedup vs baseline: 1.7009x; 1.6634x over previous
//
#include <hip/hip_runtime.h>
#include <stdint.h>
#include <float.h>

// x[4096,256] f32, keys[65536,256] f32, values[65536,10] f32, k=8 (hardcoded).
#define B_ROWS 4096
#define N_KEYS 65536
#define DDIM 256
#define NCH 10

#define NSPLIT 8
#define SPLIT_KEYS (N_KEYS / NSPLIT)       // 8192
#define ROWS_PER_BLK 64
#define CHUNK_KEYS 64
#define NCHUNK (SPLIT_KEYS / CHUNK_KEYS)   // 128

typedef float f32x4 __attribute__((ext_vector_type(4)));
typedef short bf16x8 __attribute__((ext_vector_type(8)));

static __device__ __forceinline__ unsigned short f2bf(float f) {
  unsigned u = __float_as_uint(f);
  return (unsigned short)((u + 0x7FFFu + ((u >> 16) & 1u)) >> 16);
}
static __device__ __forceinline__ unsigned ford(float f) {
  unsigned u = __float_as_uint(f);
  return u ^ ((unsigned)((int)u >> 31) | 0x80000000u);
}
static __device__ __forceinline__ unsigned long long shfl_xor_u64(unsigned long long v, int m) {
  unsigned lo = __shfl_xor((unsigned)v, m, 64);
  unsigned hi = __shfl_xor((unsigned)(v >> 32), m, 64);
  return ((unsigned long long)hi << 32) | lo;
}
static __device__ __forceinline__ double shfl_xor_f64(double v, int m) {
  return __longlong_as_double((long long)shfl_xor_u64((unsigned long long)__double_as_longlong(v), m));
}
static __device__ __forceinline__ void gl_lds16(const void* g, void* l) {
  __builtin_amdgcn_global_load_lds(
      (const __attribute__((address_space(1))) unsigned int*)g,
      (__attribute__((address_space(3))) unsigned int*)l, 16, 0, 0);
}

// ---------------------------------------------------------------------------
// transpose_keys: bf16-convert + transpose + fused ksq. Output: per 64-key
// record [doct 0..31][key 0..63][16B] (32KB): knn_main staging is a LINEAR
// copy; A-frag ds_read_b128s are 256B-contiguous per 16-lane phase.
// ---------------------------------------------------------------------------
__global__ __launch_bounds__(256) void transpose_keys(const float* __restrict__ keys,
                                                      unsigned char* __restrict__ kbf,
                                                      float* __restrict__ ksq) {
  __shared__ __align__(16) unsigned char T[128 * 512];
  const int t = threadIdx.x;
  const int lane = t & 63;
  const float4* src = (const float4*)(keys + (size_t)blockIdx.x * 128 * DDIM);
#pragma unroll
  for (int j = 0; j < 32; ++j) {
    int g = j * 256 + t;
    float4 v = src[g];
    int key = g >> 6;
    int u = lane >> 1, sub = lane & 1;
    unsigned lo = ((unsigned)f2bf(v.y) << 16) | f2bf(v.x);
    unsigned hi2 = ((unsigned)f2bf(v.w) << 16) | f2bf(v.z);
    unsigned long long p = ((unsigned long long)hi2 << 32) | lo;
    *(unsigned long long*)&T[key * 512 + ((u ^ (key & 7)) << 4) + (sub << 3)] = p;
    float ss = v.x * v.x + v.y * v.y + v.z * v.z + v.w * v.w;
#pragma unroll
    for (int off = 32; off; off >>= 1) ss += __shfl_xor(ss, off, 64);
    if (lane == 0) ksq[blockIdx.x * 128 + key] = ss;
  }
  __syncthreads();
  uint4* dst = (uint4*)(kbf + (size_t)blockIdx.x * 65536);
#pragma unroll
  for (int j = 0; j < 16; ++j) {
    int ou = j * 256 + t;
    int c64 = ou >> 11, rem = ou & 2047;
    int koct = rem >> 6, key64 = rem & 63;
    int keyl = c64 * 64 + key64;
    dst[ou] = *(const uint4*)&T[keyl * 512 + ((koct ^ (keyl & 7)) << 4)];
  }
}

// ---------------------------------------------------------------------------
// knn_main (r9 champion + TWIN-BLOCK TIME STAGGER):
// 512 thr = 8 waves = 4 key-quarters (mw, 16 keys) x 2 row-halves (ws, 32
// rows = 2 reg sets). 64 rows x one 8192-key split in 128 chunks of 64 keys.
// 2 blocks/CU. r9 evidence: chunk time (2170cy) ~= SUM of pipe times
// (MFMA 620 + VALU 680 + LDS/stage 870) -> twin blocks burst the same pipe
// simultaneously. Fix: twin block sleeps ~half a chunk ONCE at entry
// (s_sleep 17 ~= 1088cy); identical loop durations preserve the offset, so
// one block's MFMA/VALU burst overlaps the other's stage/LDS burst.
// Chunk rotation (addresses) kept for L2 decorrelation. ksq folded into the
// MFMA C-init (x pre-scaled by -2): scores come straight out of the
// accumulator. Selection: tau filter + append (8 paired streams/row;
// tau_row = max of 8 stream minima >= true 8th-best; overflow -> exact
// rescan in refine, correctness unconditional).
// ---------------------------------------------------------------------------
__global__ __launch_bounds__(512, 4) void knn_main(
    const float* __restrict__ x,
    const unsigned char* __restrict__ kbf,
    const float* __restrict__ ksqg,
    unsigned int* __restrict__ pools,
    unsigned int* __restrict__ counts,
    int CAP) {
  __shared__ __align__(16) unsigned char tiles[2][32768]; // 64KB double buffer
  __shared__ float tauh[2][2][16][4]; // [set][ws][lo4][mw]; monotone, race-benign
  __shared__ unsigned int rowcnt[64];

  const int t = threadIdx.x;
  const int lane = t & 63;
  const int wv = t >> 6;          // 0..7
  const int mw = wv & 3;          // key quarter (16 keys)
  const int ws = wv >> 2;         // row half (32 rows)
  const int lo4 = lane & 15;
  const int hi = lane >> 4;

  const int split = blockIdx.x & (NSPLIT - 1);
  const int rb = (blockIdx.x >> 3) * ROWS_PER_BLK;
  const int sb = split * SPLIT_KEYS;
  const int twin = (blockIdx.x >> 8) & 1;
  const int rot = twin * (NCHUNK / 2); // de-phase twin block (addresses)

  // ---- TIME stagger: twin sleeps ~half a chunk once; offset persists
  if (twin) {
    __builtin_amdgcn_s_sleep(17); // ~1088 cyc
  }

  const int xrow0 = rb + ws * 32 + lo4;
  const int xrow1 = xrow0 + 16;
  const int rl0 = ws * 32 + lo4, rl1 = rl0 + 16;

  // ---- x fragments PRE-SCALED by -2 (folds the -2 into the MFMA)
  bf16x8 xb0[8], xb1[8];
#pragma unroll
  for (int s = 0; s < 8; ++s) {
    const float* p0 = x + (size_t)xrow0 * DDIM + s * 32 + hi * 8;
    const float* p1 = x + (size_t)xrow1 * DDIM + s * 32 + hi * 8;
    float4 a = *(const float4*)p0, b = *(const float4*)(p0 + 4);
    float4 c = *(const float4*)p1, d = *(const float4*)(p1 + 4);
    union { unsigned short us[8]; bf16x8 v; } u0, u1;
    u0.us[0]=f2bf(-2.f*a.x); u0.us[1]=f2bf(-2.f*a.y); u0.us[2]=f2bf(-2.f*a.z); u0.us[3]=f2bf(-2.f*a.w);
    u0.us[4]=f2bf(-2.f*b.x); u0.us[5]=f2bf(-2.f*b.y); u0.us[6]=f2bf(-2.f*b.z); u0.us[7]=f2bf(-2.f*b.w);
    u1.us[0]=f2bf(-2.f*c.x); u1.us[1]=f2bf(-2.f*c.y); u1.us[2]=f2bf(-2.f*c.z); u1.us[3]=f2bf(-2.f*c.w);
    u1.us[4]=f2bf(-2.f*d.x); u1.us[5]=f2bf(-2.f*d.y); u1.us[6]=f2bf(-2.f*d.z); u1.us[7]=f2bf(-2.f*d.w);
    xb0[s] = u0.v; xb1[s] = u1.v;
  }

  if (t < 64) rowcnt[t] = 0;

  float smin0 = FLT_MAX, smin1 = FLT_MAX;
  const unsigned char* srcbase = kbf + ((size_t)(split * NCHUNK) << 15);
  const size_t pb0 = ((size_t)xrow0 * NSPLIT + split) * (size_t)CAP;
  const size_t pb1 = ((size_t)xrow1 * NSPLIT + split) * (size_t)CAP;

  auto CIDX = [&](int c) { return (c + rot) & (NCHUNK - 1); };

  auto STAGE = [&](int c, int buf) { // linear 32KB, 4 x 16B per thread
    const unsigned char* src = srcbase + ((size_t)CIDX(c) << 15);
    unsigned char* wb = (unsigned char*)tiles[buf] + ((wv * 64) << 4);
#pragma unroll
    for (int i = 0; i < 4; ++i)
      gl_lds16(src + (((i * 512) + t) << 4), wb + ((i * 512) << 4));
  };
  auto LOADQ = [&](int c) {
    return *(const float4*)(ksqg + sb + CIDX(c) * CHUNK_KEYS + mw * 16 + hi * 4);
  };

  f32x4 a0, a1;
  float4 kqc, kqn;

  auto COMPUTE = [&](int c) { // acc init = ksq (fold), then MFMA
    const unsigned char* tile = tiles[c & 1];
    f32x4 ini;
    ini[0] = kqc.x; ini[1] = kqc.y; ini[2] = kqc.z; ini[3] = kqc.w;
    a0 = ini; a1 = ini;
    __builtin_amdgcn_s_setprio(1);
#pragma unroll
    for (int s = 0; s < 8; ++s) {
      const unsigned char* rp = tile + (s * 4 + hi) * 1024 + (mw * 16 + lo4) * 16;
      bf16x8 af = *(const bf16x8*)rp;
      a0 = __builtin_amdgcn_mfma_f32_16x16x32_bf16(af, xb0[s], a0, 0, 0, 0);
      a1 = __builtin_amdgcn_mfma_f32_16x16x32_bf16(af, xb1[s], a1, 0, 0, 0);
    }
    __builtin_amdgcn_s_setprio(0);
  };

  auto SEL = [&](int c, bool append, float tau0, float tau1) {
    // scores are the accumulators directly (ksq - 2*x.k)
    float mb0 = fminf(fminf(a0[0], a0[1]), fminf(a0[2], a0[3]));
    float mb1 = fminf(fminf(a1[0], a1[1]), fminf(a1[2], a1[3]));
    smin0 = fminf(smin0, mb0);
    smin1 = fminf(smin1, mb1);
    if (append) {
      const int kloc = CIDX(c) * CHUNK_KEYS + mw * 16 + hi * 4;
      if (mb0 <= tau0) { // rare
#pragma unroll
        for (int i = 0; i < 4; ++i) {
          if (a0[i] <= tau0) {
            unsigned slot = atomicAdd(&rowcnt[rl0], 1u);
            if ((int)slot < CAP)
              pools[pb0 + slot] = (ford(a0[i]) & 0xFFFFE000u) | (unsigned)(kloc + i);
          }
        }
      }
      if (mb1 <= tau1) {
#pragma unroll
        for (int i = 0; i < 4; ++i) {
          if (a1[i] <= tau1) {
            unsigned slot = atomicAdd(&rowcnt[rl1], 1u);
            if ((int)slot < CAP)
              pools[pb1 + slot] = (ford(a1[i]) & 0xFFFFE000u) | (unsigned)(kloc + i);
          }
        }
      }
    }
  };

  auto RDTAU = [&](float& tau0, float& tau1) {
    float4 t0 = *(const float4*)&tauh[0][ws][lo4][0];
    float4 t1 = *(const float4*)&tauh[1][ws][lo4][0];
    tau0 = fmaxf(fmaxf(t0.x, t0.y), fmaxf(t0.z, t0.w));
    tau1 = fmaxf(fmaxf(t1.x, t1.y), fmaxf(t1.z, t1.w));
  };

  auto PUBLISH = [&]() {
    // pair streams across hi (xor16 -> min), then max over the 2 pairs (xor32)
    float p0 = fminf(smin0, __shfl_xor(smin0, 16, 64));
    p0 = fmaxf(p0, __shfl_xor(p0, 32, 64));
    float p1 = fminf(smin1, __shfl_xor(smin1, 16, 64));
    p1 = fmaxf(p1, __shfl_xor(p1, 32, 64));
    if (hi == 0) {
      tauh[0][ws][lo4][mw] = p0;
      tauh[1][ws][lo4][mw] = p1;
    }
  };

  // ---- prologue + peeled chunk 0 (build tau before any appends)
  STAGE(0, 0);
  kqc = LOADQ(0);
  __syncthreads();
  STAGE(1, 1);
  kqn = LOADQ(1);
  COMPUTE(0);
  SEL(0, false, 0.f, 0.f);   // smin only
  PUBLISH();
  __syncthreads();           // tau visible (drains stage(1) too — prologue only)
  {
    float tau0, tau1;
    RDTAU(tau0, tau1);
    SEL(0, true, tau0, tau1); // append chunk 0 with fresh tau
  }
  kqc = kqn;

#pragma unroll 1
  for (int c = 1; c < NCHUNK; ++c) {
    const int cn = (c + 1 < NCHUNK) ? c + 1 : c; // uniform tail (re-stage ok)
    STAGE(cn, (c + 1) & 1);
    kqn = LOADQ(cn);
    float tau0, tau1;
    RDTAU(tau0, tau1);       // lagged/racy tau: always a valid upper bound
    COMPUTE(c);
    SEL(c, true, tau0, tau1);
    if (c & 1) PUBLISH();
    kqc = kqn;
    __syncthreads();         // tile consumed; next stage drained
  }

  __syncthreads();
  if (t < 64) counts[(size_t)(rb + t) * NSPLIT + split] = rowcnt[t];
}

// ---------------------------------------------------------------------------
// knn_refine: per row (1 wave): scan the row's 8 pools (or exact-rescan any
// overflowed split) into per-lane top-8, tournament top-24 by quantized
// score, fp64-exact recompute, true top-8 (idx tiebreak), average values.
// ---------------------------------------------------------------------------
__global__ __launch_bounds__(64) void knn_refine(
    const float* __restrict__ x,
    const float* __restrict__ keys,
    const float* __restrict__ ksq,
    const float* __restrict__ values,
    const unsigned int* __restrict__ pools,
    const unsigned int* __restrict__ counts,
    int CAP,
    float* __restrict__ out) {
  __shared__ float4 xl[64];
  const int row = blockIdx.x;
  const int lane = threadIdx.x;

  xl[lane] = ((const float4*)(x + (size_t)row * DDIM))[lane];
  __syncthreads();

  unsigned long long h[8];
#pragma unroll
  for (int i = 0; i < 8; ++i) h[i] = ~0ULL;

  auto insert = [&](unsigned long long v) {
    if (v < h[7]) {
#pragma unroll
      for (int j = 7; j >= 1; --j) {
        unsigned long long a = h[j - 1];
        unsigned long long mx = a > v ? a : v;
        h[j] = (v < h[j]) ? mx : h[j];
      }
      h[0] = h[0] < v ? h[0] : v;
    }
  };

  for (int s = 0; s < NSPLIT; ++s) {
    unsigned cnt = counts[(size_t)row * NSPLIT + s];
    if ((int)cnt <= CAP) {
      const unsigned int* pp = pools + ((size_t)row * NSPLIT + s) * (size_t)CAP;
      for (int i = lane; i < (int)cnt; i += 64) {
        unsigned p = pp[i];
        unsigned long long v = ((unsigned long long)p << 17)
                             | (unsigned)(s * SPLIT_KEYS + (p & 0x1FFFu));
        insert(v);
      }
    } else {
      // overflow fallback: exact fp32 rescan of this split
      for (int kk = lane; kk < SPLIT_KEYS; kk += 64) {
        int gk = s * SPLIT_KEYS + kk;
        const float4* kr = (const float4*)(keys + (size_t)gk * DDIM);
        float acc = 0.f;
#pragma unroll 8
        for (int d = 0; d < 64; ++d) {
          float4 kv = kr[d], xv = xl[d];
          acc = fmaf(kv.x, xv.x, acc); acc = fmaf(kv.y, xv.y, acc);
          acc = fmaf(kv.z, xv.z, acc); acc = fmaf(kv.w, xv.w, acc);
        }
        float sc = fmaf(-2.0f, acc, ksq[gk]);
        unsigned p = (ford(sc) & 0xFFFFE000u) | (unsigned)kk;
        insert(((unsigned long long)p << 17) | (unsigned)gk);
      }
    }
  }

  // ---- tournament: top-24 by quantized score (u64 unique: gk in low bits)
  int myidx = 0;
#pragma unroll 1
  for (int r = 0; r < 24; ++r) {
    unsigned long long m = h[0];
#pragma unroll
    for (int off = 32; off; off >>= 1) {
      unsigned long long o = shfl_xor_u64(m, off);
      m = o < m ? o : m;
    }
    if (lane == r) myidx = (int)(m & 0x1FFFFu);
    if (h[0] == m) {
#pragma unroll
      for (int i = 0; i < 7; ++i) h[i] = h[i + 1];
      h[7] = ~0ULL;
    }
  }

  // ---- exact fp64 distance for my candidate
  double dv = 1e300;
  if (lane < 24) {
    const float4* kr = (const float4*)(keys + (size_t)myidx * DDIM);
    double s = 0.0;
#pragma unroll 8
    for (int d = 0; d < 64; ++d) {
      float4 kv = kr[d], xv = xl[d];
      double d0 = (double)xv.x - (double)kv.x;
      double d1 = (double)xv.y - (double)kv.y;
      double d2 = (double)xv.z - (double)kv.z;
      double d3 = (double)xv.w - (double)kv.w;
      s += d0 * d0 + d1 * d1 + d2 * d2 + d3 * d3;
    }
    dv = s;
  }

  int di = myidx;
  int chosen[8];
#pragma unroll
  for (int r = 0; r < 8; ++r) {
    double m = dv; int mi = di;
#pragma unroll
    for (int off = 32; off; off >>= 1) {
      double om = shfl_xor_f64(m, off);
      int omi = __shfl_xor(mi, off, 64);
      if (om < m || (om == m && omi < mi)) { m = om; mi = omi; }
    }
    chosen[r] = mi;
    if (di == mi && dv < 1e300) dv = 1e300;
  }

  if (lane < NCH) {
    double a = 0.0;
#pragma unroll
    for (int r = 0; r < 8; ++r) a += (double)values[(size_t)chosen[r] * NCH + lane];
    out[row * NCH + lane] = (float)(a * 0.125);
  }
}

// ---------------------------------------------------------------------------
extern "C" void kernel_launch(void* const* d_in, const int* in_sizes, int n_in,
                              void* d_out, int out_size, void* d_ws, size_t ws_size,
                              hipStream_t stream) {
  (void)in_sizes; (void)n_in; (void)out_size;
  const float* x      = (const float*)d_in[0];
  const float* keys   = (const float*)d_in[1];
  const float* values = (const float*)d_in[2];
  float* out = (float*)d_out;

  char* ws = (char*)d_ws;
  unsigned char* kbf = (unsigned char*)ws;                            // 32 MB transposed bf16 keys
  float* ksq   = (float*)(ws + 33554432);                             // 256 KB
  unsigned int* counts = (unsigned int*)(ws + 33554432 + 262144);     // 128 KB
  unsigned int* pools  = (unsigned int*)(ws + 33554432 + 262144 + 131072);

  size_t base = 33554432 + 262144 + 131072;
  size_t cap = (ws_size > base) ? (ws_size - base) / ((size_t)B_ROWS * NSPLIT * 4) : 32;
  if (cap < 32) cap = 32;
  if (cap > 2048) cap = 2048;
  int CAP = (int)cap;

  transpose_keys<<<N_KEYS / 128, 256, 0, stream>>>(keys, kbf, ksq);
  knn_main<<<(B_ROWS / ROWS_PER_BLK) * NSPLIT, 512, 0, stream>>>(
      x, kbf, ksq, pools, counts, CAP);
  knn_refine<<<B_ROWS, 64, 0, stream>>>(x, keys, ksq, values, pools, counts, CAP, out);
}

// Round 16
// 275.956 us; speedup vs baseline: 1.8875x; 1.1097x over previous
//
#include <hip/hip_runtime.h>
#include <stdint.h>
#include <float.h>

// x[4096,256] f32, keys[65536,256] f32, values[65536,10] f32, k=8 (hardcoded).
#define B_ROWS 4096
#define N_KEYS 65536
#define DDIM 256
#define NCH 10

#define NSPLIT 16
#define SPLIT_KEYS (N_KEYS / NSPLIT)       // 4096
#define ROWS_PER_BLK 128
#define CHUNK_KEYS 32
#define NCHUNK (SPLIT_KEYS / CHUNK_KEYS)   // 128

typedef float f32x4 __attribute__((ext_vector_type(4)));
typedef short bf16x8 __attribute__((ext_vector_type(8)));

static __device__ __forceinline__ unsigned short f2bf(float f) {
  unsigned u = __float_as_uint(f);
  return (unsigned short)((u + 0x7FFFu + ((u >> 16) & 1u)) >> 16);
}
static __device__ __forceinline__ unsigned ford(float f) {
  unsigned u = __float_as_uint(f);
  return u ^ ((unsigned)((int)u >> 31) | 0x80000000u);
}
static __device__ __forceinline__ unsigned long long shfl_xor_u64(unsigned long long v, int m) {
  unsigned lo = __shfl_xor((unsigned)v, m, 64);
  unsigned hi = __shfl_xor((unsigned)(v >> 32), m, 64);
  return ((unsigned long long)hi << 32) | lo;
}
static __device__ __forceinline__ double shfl_xor_f64(double v, int m) {
  return __longlong_as_double((long long)shfl_xor_u64((unsigned long long)__double_as_longlong(v), m));
}
static __device__ __forceinline__ void gl_lds16(const void* g, void* l) {
  __builtin_amdgcn_global_load_lds(
      (const __attribute__((address_space(1))) unsigned int*)g,
      (__attribute__((address_space(3))) unsigned int*)l, 16, 0, 0);
}

// ---------------------------------------------------------------------------
// transpose_keys: bf16-convert + transpose + fused ksq. Output: per 32-key
// record [koct 0..31][key 0..31][16B] (16KB): knn_main staging is a LINEAR
// copy; A-frag ds_read_b128s are 256B-contiguous per 16-lane phase.
// ---------------------------------------------------------------------------
__global__ __launch_bounds__(256) void transpose_keys(const float* __restrict__ keys,
                                                      unsigned char* __restrict__ kbf,
                                                      float* __restrict__ ksq) {
  __shared__ __align__(16) unsigned char T[128 * 512];
  const int t = threadIdx.x;
  const int lane = t & 63;
  const float4* src = (const float4*)(keys + (size_t)blockIdx.x * 128 * DDIM);
#pragma unroll
  for (int j = 0; j < 32; ++j) {
    int g = j * 256 + t;
    float4 v = src[g];
    int key = g >> 6;
    int u = lane >> 1, sub = lane & 1;
    unsigned lo = ((unsigned)f2bf(v.y) << 16) | f2bf(v.x);
    unsigned hi2 = ((unsigned)f2bf(v.w) << 16) | f2bf(v.z);
    unsigned long long p = ((unsigned long long)hi2 << 32) | lo;
    *(unsigned long long*)&T[key * 512 + ((u ^ (key & 7)) << 4) + (sub << 3)] = p;
    float ss = v.x * v.x + v.y * v.y + v.z * v.z + v.w * v.w;
#pragma unroll
    for (int off = 32; off; off >>= 1) ss += __shfl_xor(ss, off, 64);
    if (lane == 0) ksq[blockIdx.x * 128 + key] = ss;
  }
  __syncthreads();
  uint4* dst = (uint4*)kbf + (size_t)blockIdx.x * 4096; // 4 records of 1024 units
#pragma unroll
  for (int j = 0; j < 16; ++j) {
    int ou = j * 256 + t;                 // rec(4) x koct(32) x key32(32)
    int rec = ou >> 10, rem = ou & 1023;
    int koct = rem >> 5, key32 = rem & 31;
    int keyl = rec * 32 + key32;
    dst[ou] = *(const uint4*)&T[keyl * 512 + ((koct ^ (keyl & 7)) << 4)];
  }
}

// ---------------------------------------------------------------------------
// knn_main (r9 convoy + T3/T4 counted-vmcnt 4-buffer ring + 2x row amort.):
// 512 thr = 8 waves = 2 key-halves (mw, 16 keys) x 4 row-groups (ws, 32 rows
// = 2 reg sets, feed-2). Block: 128 rows x one 4096-key split in 128 chunks
// of 32 keys. 2 blocks/CU (VGPR-capped 16 waves/CU). 4-buffer LDS ring with
// lookahead-2: per chunk ONE raw s_barrier preceded by s_waitcnt vmcnt(4) —
// the next 2 chunks' staging loads stay IN FLIGHT across the barrier (never
// drains; pool atomics only make the wait conservative, never unsafe).
// Ring safety: STAGE(c+3) overwrites buf((c+3)&3)=buf((c-1)&3), last read in
// period c-1; any wave past period-c's barrier has executed its period-(c-1)
// MFMAs (which waited on those ds_reads), so no wave can still be reading it.
// ksq folded into MFMA C-init (x pre-scaled by -2): scores = accumulator.
// Selection: tau filter + append (8 streams/row = hi(4) x mw(2); tau_row =
// max of 8 stream minima >= true 8th-best; overflow -> per-split exact
// rescan in refine, correctness unconditional).
// ---------------------------------------------------------------------------
__global__ __launch_bounds__(512, 4) void knn_main(
    const float* __restrict__ x,
    const unsigned char* __restrict__ kbf,
    const float* __restrict__ ksqg,
    unsigned int* __restrict__ pools,
    unsigned int* __restrict__ counts,
    int CAP) {
  __shared__ __align__(16) unsigned char tiles[4][16384]; // 64KB ring
  __shared__ float tauh[2][4][16][2]; // [set][ws][lo4][mw]; monotone
  __shared__ unsigned int rowcnt[128];

  const int t = threadIdx.x;
  const int lane = t & 63;
  const int wv = t >> 6;          // 0..7
  const int mw = wv & 1;          // key half (16 keys)
  const int ws = wv >> 1;         // row group (32 rows)
  const int lo4 = lane & 15;
  const int hi = lane >> 4;

  const int split = blockIdx.x & (NSPLIT - 1);
  const int rb = (blockIdx.x >> 4) * ROWS_PER_BLK;
  const int sb = split * SPLIT_KEYS;

  const int xrow0 = rb + ws * 32 + lo4;
  const int xrow1 = xrow0 + 16;
  const int rl0 = ws * 32 + lo4, rl1 = rl0 + 16;

  // ---- x fragments PRE-SCALED by -2 (folds the -2 into the MFMA)
  bf16x8 xb0[8], xb1[8];
#pragma unroll
  for (int s = 0; s < 8; ++s) {
    const float* p0 = x + (size_t)xrow0 * DDIM + s * 32 + hi * 8;
    const float* p1 = x + (size_t)xrow1 * DDIM + s * 32 + hi * 8;
    float4 a = *(const float4*)p0, b = *(const float4*)(p0 + 4);
    float4 c = *(const float4*)p1, d = *(const float4*)(p1 + 4);
    union { unsigned short us[8]; bf16x8 v; } u0, u1;
    u0.us[0]=f2bf(-2.f*a.x); u0.us[1]=f2bf(-2.f*a.y); u0.us[2]=f2bf(-2.f*a.z); u0.us[3]=f2bf(-2.f*a.w);
    u0.us[4]=f2bf(-2.f*b.x); u0.us[5]=f2bf(-2.f*b.y); u0.us[6]=f2bf(-2.f*b.z); u0.us[7]=f2bf(-2.f*b.w);
    u1.us[0]=f2bf(-2.f*c.x); u1.us[1]=f2bf(-2.f*c.y); u1.us[2]=f2bf(-2.f*c.z); u1.us[3]=f2bf(-2.f*c.w);
    u1.us[4]=f2bf(-2.f*d.x); u1.us[5]=f2bf(-2.f*d.y); u1.us[6]=f2bf(-2.f*d.z); u1.us[7]=f2bf(-2.f*d.w);
    xb0[s] = u0.v; xb1[s] = u1.v;
  }

  if (t < 128) rowcnt[t] = 0;

  float smin0 = FLT_MAX, smin1 = FLT_MAX;
  const unsigned char* srcbase = kbf + ((size_t)(split * NCHUNK) << 14);
  const size_t pb0 = ((size_t)xrow0 * NSPLIT + split) * (size_t)CAP;
  const size_t pb1 = ((size_t)xrow1 * NSPLIT + split) * (size_t)CAP;

  auto STAGE = [&](int c, int buf) { // linear 16KB, 2 x 16B per thread
    const unsigned char* src = srcbase + ((size_t)c << 14);
#pragma unroll
    for (int i = 0; i < 2; ++i)
      gl_lds16(src + (((i * 512) + t) << 4),
               (unsigned char*)tiles[buf] + ((i * 512 + wv * 64) << 4));
  };
  auto LOADQ = [&](int c) {
    return *(const float4*)(ksqg + sb + c * CHUNK_KEYS + mw * 16 + hi * 4);
  };

  f32x4 a0, a1;
  float4 kqc, kqn;

  auto COMPUTE = [&](int buf) { // acc init = ksq (fold), then MFMA
    const unsigned char* tile = tiles[buf];
    f32x4 ini;
    ini[0] = kqc.x; ini[1] = kqc.y; ini[2] = kqc.z; ini[3] = kqc.w;
    a0 = ini; a1 = ini;
    __builtin_amdgcn_s_setprio(1);
#pragma unroll
    for (int s = 0; s < 8; ++s) {
      const unsigned char* rp = tile + (s * 4 + hi) * 512 + (mw * 16 + lo4) * 16;
      bf16x8 af = *(const bf16x8*)rp;
      a0 = __builtin_amdgcn_mfma_f32_16x16x32_bf16(af, xb0[s], a0, 0, 0, 0);
      a1 = __builtin_amdgcn_mfma_f32_16x16x32_bf16(af, xb1[s], a1, 0, 0, 0);
    }
    __builtin_amdgcn_s_setprio(0);
  };

  auto SEL = [&](int c, bool append, float tau0, float tau1) {
    float mb0 = fminf(fminf(a0[0], a0[1]), fminf(a0[2], a0[3]));
    float mb1 = fminf(fminf(a1[0], a1[1]), fminf(a1[2], a1[3]));
    smin0 = fminf(smin0, mb0);
    smin1 = fminf(smin1, mb1);
    if (append) {
      const int kloc = c * CHUNK_KEYS + mw * 16 + hi * 4; // 12-bit local idx
      if (mb0 <= tau0) { // rare
#pragma unroll
        for (int i = 0; i < 4; ++i) {
          if (a0[i] <= tau0) {
            unsigned slot = atomicAdd(&rowcnt[rl0], 1u);
            if ((int)slot < CAP)
              pools[pb0 + slot] = (ford(a0[i]) & 0xFFFFF000u) | (unsigned)(kloc + i);
          }
        }
      }
      if (mb1 <= tau1) {
#pragma unroll
        for (int i = 0; i < 4; ++i) {
          if (a1[i] <= tau1) {
            unsigned slot = atomicAdd(&rowcnt[rl1], 1u);
            if ((int)slot < CAP)
              pools[pb1 + slot] = (ford(a1[i]) & 0xFFFFF000u) | (unsigned)(kloc + i);
          }
        }
      }
    }
  };

  auto RDTAU = [&](float& tau0, float& tau1) { // max over both mw entries
    tau0 = fmaxf(tauh[0][ws][lo4][0], tauh[0][ws][lo4][1]);
    tau1 = fmaxf(tauh[1][ws][lo4][0], tauh[1][ws][lo4][1]);
  };

  auto PUBLISH = [&]() { // per wave: max over its 4 hi-stream minima
    float p0 = fmaxf(smin0, __shfl_xor(smin0, 16, 64));
    p0 = fmaxf(p0, __shfl_xor(p0, 32, 64));
    float p1 = fmaxf(smin1, __shfl_xor(smin1, 16, 64));
    p1 = fmaxf(p1, __shfl_xor(p1, 32, 64));
    if (hi == 0) {
      tauh[0][ws][lo4][mw] = p0;
      tauh[1][ws][lo4][mw] = p1;
    }
  };

  // ---- prologue: tau from chunks 0 and 64 (minima only), then prime ring
  STAGE(0, 0);
  STAGE(64, 1);
  __syncthreads();               // full drain (prologue only)
  kqc = LOADQ(0);
  COMPUTE(0); SEL(0, false, 0.f, 0.f);
  kqc = LOADQ(64);
  COMPUTE(1); SEL(64, false, 0.f, 0.f);
  PUBLISH();
  __syncthreads();               // tauh visible; prologue reads done
  STAGE(1, 1);                   // chunk 0 still valid in buf 0
  STAGE(2, 2);
  kqc = LOADQ(0);
  kqn = LOADQ(1);

#pragma unroll 1
  for (int c = 0; c < NCHUNK; ++c) {
    asm volatile("s_waitcnt vmcnt(4)" ::: "memory"); // chunk c landed; c+1,c+2 in flight
    __builtin_amdgcn_s_barrier();
    float tau0, tau1;
    RDTAU(tau0, tau1);           // lagged/racy tau: always a valid upper bound
    COMPUTE(c & 3);
    SEL(c, true, tau0, tau1);
    if (c & 1) PUBLISH();
    kqc = kqn;
    kqn = LOADQ((c + 2 < NCHUNK) ? c + 2 : 0);
    const int cs = (c + 3 < NCHUNK) ? c + 3 : c + 3 - NCHUNK; // wrap: dummy
    STAGE(cs, (c + 3) & 3);
  }

  __syncthreads();
  if (t < 128) counts[(size_t)(rb + t) * NSPLIT + split] = rowcnt[t];
}

// ---------------------------------------------------------------------------
// knn_refine: per row (1 wave): scan the row's 16 pools (overflowed split ->
// exact fp32 rescan of THAT 4096-key split), tournament top-24 by quantized
// score, fp64-exact recompute, true top-8 (idx tiebreak), average values.
// ---------------------------------------------------------------------------
__global__ __launch_bounds__(64) void knn_refine(
    const float* __restrict__ x,
    const float* __restrict__ keys,
    const float* __restrict__ ksq,
    const float* __restrict__ values,
    const unsigned int* __restrict__ pools,
    const unsigned int* __restrict__ counts,
    int CAP,
    float* __restrict__ out) {
  __shared__ float4 xl[64];
  const int row = blockIdx.x;
  const int lane = threadIdx.x;

  xl[lane] = ((const float4*)(x + (size_t)row * DDIM))[lane];
  __syncthreads();

  unsigned long long h[8];
#pragma unroll
  for (int i = 0; i < 8; ++i) h[i] = ~0ULL;

  auto insert = [&](unsigned long long v) {
    if (v < h[7]) {
#pragma unroll
      for (int j = 7; j >= 1; --j) {
        unsigned long long a = h[j - 1];
        unsigned long long mx = a > v ? a : v;
        h[j] = (v < h[j]) ? mx : h[j];
      }
      h[0] = h[0] < v ? h[0] : v;
    }
  };

  for (int s = 0; s < NSPLIT; ++s) {
    unsigned cnt = counts[(size_t)row * NSPLIT + s];
    if ((int)cnt <= CAP) {
      const unsigned int* pp = pools + ((size_t)row * NSPLIT + s) * (size_t)CAP;
      for (int i = lane; i < (int)cnt; i += 64) {
        unsigned p = pp[i];
        unsigned gk = (unsigned)(s * SPLIT_KEYS) + (p & 0xFFFu);
        insert(((unsigned long long)(p & 0xFFFFF000u) << 16) | gk);
      }
    } else {
      // overflow fallback: exact fp32 rescan of this 4096-key split
      for (int kk = lane; kk < SPLIT_KEYS; kk += 64) {
        int gk = s * SPLIT_KEYS + kk;
        const float4* kr = (const float4*)(keys + (size_t)gk * DDIM);
        float acc = 0.f;
#pragma unroll 8
        for (int d = 0; d < 64; ++d) {
          float4 kv = kr[d], xv = xl[d];
          acc = fmaf(kv.x, xv.x, acc); acc = fmaf(kv.y, xv.y, acc);
          acc = fmaf(kv.z, xv.z, acc); acc = fmaf(kv.w, xv.w, acc);
        }
        float sc = fmaf(-2.0f, acc, ksq[gk]);
        insert(((unsigned long long)(ford(sc) & 0xFFFFF000u) << 16) | (unsigned)gk);
      }
    }
  }

  // ---- tournament: top-24 by quantized score (u64 unique: gk in low 16b)
  int myidx = 0;
#pragma unroll 1
  for (int r = 0; r < 24; ++r) {
    unsigned long long m = h[0];
#pragma unroll
    for (int off = 32; off; off >>= 1) {
      unsigned long long o = shfl_xor_u64(m, off);
      m = o < m ? o : m;
    }
    if (lane == r) myidx = (int)(m & 0xFFFFu);
    if (h[0] == m) {
#pragma unroll
      for (int i = 0; i < 7; ++i) h[i] = h[i + 1];
      h[7] = ~0ULL;
    }
  }

  // ---- exact fp64 distance for my candidate
  double dv = 1e300;
  if (lane < 24) {
    const float4* kr = (const float4*)(keys + (size_t)myidx * DDIM);
    double s = 0.0;
#pragma unroll 8
    for (int d = 0; d < 64; ++d) {
      float4 kv = kr[d], xv = xl[d];
      double d0 = (double)xv.x - (double)kv.x;
      double d1 = (double)xv.y - (double)kv.y;
      double d2 = (double)xv.z - (double)kv.z;
      double d3 = (double)xv.w - (double)kv.w;
      s += d0 * d0 + d1 * d1 + d2 * d2 + d3 * d3;
    }
    dv = s;
  }

  int di = myidx;
  int chosen[8];
#pragma unroll
  for (int r = 0; r < 8; ++r) {
    double m = dv; int mi = di;
#pragma unroll
    for (int off = 32; off; off >>= 1) {
      double om = shfl_xor_f64(m, off);
      int omi = __shfl_xor(mi, off, 64);
      if (om < m || (om == m && omi < mi)) { m = om; mi = omi; }
    }
    chosen[r] = mi;
    if (di == mi && dv < 1e300) dv = 1e300;
  }

  if (lane < NCH) {
    double a = 0.0;
#pragma unroll
    for (int r = 0; r < 8; ++r) a += (double)values[(size_t)chosen[r] * NCH + lane];
    out[row * NCH + lane] = (float)(a * 0.125);
  }
}

// ---------------------------------------------------------------------------
extern "C" void kernel_launch(void* const* d_in, const int* in_sizes, int n_in,
                              void* d_out, int out_size, void* d_ws, size_t ws_size,
                              hipStream_t stream) {
  (void)in_sizes; (void)n_in; (void)out_size;
  const float* x      = (const float*)d_in[0];
  const float* keys   = (const float*)d_in[1];
  const float* values = (const float*)d_in[2];
  float* out = (float*)d_out;

  char* ws = (char*)d_ws;
  unsigned char* kbf = (unsigned char*)ws;                            // 32 MB transposed bf16 keys
  float* ksq   = (float*)(ws + 33554432);                             // 256 KB
  unsigned int* counts = (unsigned int*)(ws + 33554432 + 262144);     // 256 KB (4096x16)
  unsigned int* pools  = (unsigned int*)(ws + 33554432 + 262144 + 262144);

  size_t base = 33554432 + 262144 + 262144;
  size_t cap = (ws_size > base) ? (ws_size - base) / ((size_t)B_ROWS * NSPLIT * 4) : 60;
  if (cap < 60) cap = 60;      // 60 -> pool ends <49.8 MB (< proven 50.6)
  if (cap > 512) cap = 512;
  int CAP = (int)cap;

  transpose_keys<<<N_KEYS / 128, 256, 0, stream>>>(keys, kbf, ksq);
  knn_main<<<(B_ROWS / ROWS_PER_BLK) * NSPLIT, 512, 0, stream>>>(
      x, kbf, ksq, pools, counts, CAP);
  knn_refine<<<B_ROWS, 64, 0, stream>>>(x, keys, ksq, values, pools, counts, CAP, out);
}